// Round 7
// baseline (225.456 us; speedup 1.0000x reference)
//
#include <hip/hip_runtime.h>
#include <math.h>

#define EMB 512
#define VQ 32
#define MCODES 32   // 2*LOG2
#define EPS 1e-8f

// ---------------------------------------------------------------------------
// prep: normalize codebook rows, G = 2*En, q = ||En||^2, C = En @ W_inv
// grid = 32 blocks (one per codebook row), 256 threads
// ---------------------------------------------------------------------------
__global__ __launch_bounds__(256)
void prep_kernel(const float* __restrict__ emb, const float* __restrict__ W_inv,
                 float* __restrict__ Cw, float* __restrict__ G, float* __restrict__ qv,
                 float* __restrict__ loss_out) {
  const int b = blockIdx.x;
  const int tid = threadIdx.x;
  __shared__ float En_s[VQ];
  float ss = 0.f;
#pragma unroll
  for (int d = 0; d < VQ; ++d) { float v = emb[b * VQ + d]; ss += v * v; }
  const float inv = 1.0f / (sqrtf(ss) + EPS);
  if (tid < VQ) En_s[tid] = emb[b * VQ + tid] * inv;
  __syncthreads();
  float a0 = 0.f, a1 = 0.f;
#pragma unroll 8
  for (int d = 0; d < VQ; ++d) {
    const float en = En_s[d];
    const float2 wv = ((const float2*)(W_inv + d * EMB))[tid];
    a0 += en * wv.x;
    a1 += en * wv.y;
  }
  ((float2*)(Cw + b * EMB))[tid] = make_float2(a0, a1);
  if (tid < VQ) G[b * VQ + tid] = 2.0f * En_s[tid];
  if (tid == 0) {
    float qq = 0.f;
#pragma unroll
    for (int d = 0; d < VQ; ++d) qq += En_s[d] * En_s[d];
    qv[b] = qq;
    if (b == 0) loss_out[0] = 0.0f;   // vq_loss
  }
}

// ---------------------------------------------------------------------------
// proj: hp = h @ W_proj + b_proj ; hn = hp/(|hp|+eps) ; pair softmax ; code
// RESTRUCTURED for occupancy: 32 tokens/block -> 2048 blocks (8 blocks/CU,
// 32 waves/CU) instead of 512 blocks (2/CU, the round-6 latency bottleneck:
// Occupancy 19%, VALUBusy 16%). One token x 4 dims per thread; math verbatim.
// ---------------------------------------------------------------------------
__global__ __launch_bounds__(256)
void proj_kernel(const float* __restrict__ h, const int* __restrict__ mask,
                 const float* __restrict__ W_proj, const float* __restrict__ b_proj,
                 const float* __restrict__ G, const float* __restrict__ qv,
                 float* __restrict__ Aout, float* __restrict__ code_out) {
  const int tid = threadIdx.x;
  const int slot = tid >> 3;   // 0..31 : token within tile
  const int dg = tid & 7;      // 0..7  : dims 4*dg .. 4*dg+3
  const int tile = blockIdx.x * 32;
  __shared__ float hp_s[32][36];   // pitch 36 to break bank conflicts

  const float4* __restrict__ h4 = (const float4*)h;
  const float4* __restrict__ W4 = (const float4*)W_proj;   // [512][8] float4

  const float4* hr0 = h4 + (size_t)(tile + slot) * (EMB / 4);

  float4 a0 = make_float4(0.f, 0.f, 0.f, 0.f);

  for (int e4 = 0; e4 < EMB / 4; ++e4) {
    const int eb = e4 << 2;
    const float4 w0 = W4[(eb + 0) * 8 + dg];
    const float4 w1 = W4[(eb + 1) * 8 + dg];
    const float4 w2 = W4[(eb + 2) * 8 + dg];
    const float4 w3 = W4[(eb + 3) * 8 + dg];
    const float4 v0 = hr0[e4];
    a0.x += v0.x * w0.x; a0.x += v0.y * w1.x; a0.x += v0.z * w2.x; a0.x += v0.w * w3.x;
    a0.y += v0.x * w0.y; a0.y += v0.y * w1.y; a0.y += v0.z * w2.y; a0.y += v0.w * w3.y;
    a0.z += v0.x * w0.z; a0.z += v0.y * w1.z; a0.z += v0.z * w2.z; a0.z += v0.w * w3.z;
    a0.w += v0.x * w0.w; a0.w += v0.y * w1.w; a0.w += v0.z * w2.w; a0.w += v0.w * w3.w;
  }
  *(float4*)&hp_s[slot][dg * 4] = a0;
  __syncthreads();

  if (tid < 32) {
    const int t = tile + tid;
    const float4* bp4 = (const float4*)b_proj;
    float4 hp[8];
    float ssum = 0.f;
#pragma unroll
    for (int k = 0; k < 8; ++k) {
      float4 v = *(const float4*)&hp_s[tid][k * 4];
      const float4 b = bp4[k];
      v.x += b.x; v.y += b.y; v.z += b.z; v.w += b.w;
      hp[k] = v;
      ssum += v.x * v.x + v.y * v.y + v.z * v.z + v.w * v.w;
    }
    const float inv = 1.0f / (sqrtf(ssum) + EPS);
#pragma unroll
    for (int k = 0; k < 8; ++k) {
      hp[k].x *= inv; hp[k].y *= inv; hp[k].z *= inv; hp[k].w *= inv;
    }
    const float4* G4 = (const float4*)G;   // [32][8] float4, rows = 2*En_m
    float av[32];
    int code = 0;
#pragma unroll
    for (int g = 0; g < 16; ++g) {
      float d0 = 0.f, d1 = 0.f;
#pragma unroll
      for (int k = 0; k < 8; ++k) {
        const float4 g0 = G4[(2 * g) * 8 + k];
        const float4 g1 = G4[(2 * g + 1) * 8 + k];
        const float4 hv = hp[k];
        d0 += hv.x * g0.x + hv.y * g0.y + hv.z * g0.z + hv.w * g0.w;
        d1 += hv.x * g1.x + hv.y * g1.y + hv.z * g1.z + hv.w * g1.w;
      }
      // s_m = 2*hn.En_m - ||En_m||^2  (||hn||^2 cancels inside the pair softmax)
      const float s0 = d0 - qv[2 * g];
      const float s1 = d1 - qv[2 * g + 1];
      const float mx = fmaxf(s0, s1);
      const float e0 = expf(s0 - mx);
      const float e1 = expf(s1 - mx);
      const float rs = 1.0f / (e0 + e1);
      av[2 * g] = e0 * rs;
      av[2 * g + 1] = e1 * rs;
      code |= (e1 > e0) ? (1 << g) : 0;   // argmax, first index wins ties
    }
    const int mk = mask[t];
    const float msk = (mk == 1) ? 1.0f : 0.0f;
    float4* Ao = (float4*)(Aout + (size_t)t * MCODES);
#pragma unroll
    for (int k = 0; k < 8; ++k) {
      Ao[k] = make_float4(av[4 * k] * msk, av[4 * k + 1] * msk,
                          av[4 * k + 2] * msk, av[4 * k + 3] * msk);
    }
    code_out[t] = (mk == 1) ? (float)code : 0.0f;
  }
}

// ---------------------------------------------------------------------------
// inv: quantized = A' @ C + b_inv.  C columns (e-pair) resident in registers.
// 256 threads = 4 waves x 64 lanes; wave w owns e-range [128w,128w+128).
// 64 tokens / block.   (measured ~7us incl. prep — not the bottleneck)
// ---------------------------------------------------------------------------
__global__ __launch_bounds__(256)
void inv_kernel(const float* __restrict__ Ap, const float* __restrict__ Cw,
                const float* __restrict__ b_inv, float* __restrict__ qout) {
  const int tid = threadIdx.x;
  const int w = tid >> 6;
  const int lane = tid & 63;
  const int ep = w * 64 + lane;      // e-pair index; e = 2*ep
  const int tile = blockIdx.x * 64;
  float2 c[32];
#pragma unroll
  for (int m = 0; m < 32; ++m) c[m] = ((const float2*)(Cw + m * EMB))[ep];
  const float2 bi = ((const float2*)b_inv)[ep];
  for (int tt = 0; tt < 64; ++tt) {
    const int t = tile + tt;
    const float4* a4 = (const float4*)(Ap + (size_t)t * 32);   // uniform address
    float accx = bi.x, accy = bi.y;
#pragma unroll
    for (int k = 0; k < 8; ++k) {
      const float4 a = a4[k];
      accx += a.x * c[4 * k].x + a.y * c[4 * k + 1].x + a.z * c[4 * k + 2].x + a.w * c[4 * k + 3].x;
      accy += a.x * c[4 * k].y + a.y * c[4 * k + 1].y + a.z * c[4 * k + 2].y + a.w * c[4 * k + 3].y;
    }
    ((float2*)(qout + (size_t)t * EMB))[ep] = make_float2(accx, accy);
  }
}

// ---------------------------------------------------------------------------
extern "C" void kernel_launch(void* const* d_in, const int* in_sizes, int n_in,
                              void* d_out, int out_size, void* d_ws, size_t ws_size,
                              hipStream_t stream) {
  (void)n_in; (void)out_size; (void)ws_size;
  const float* h      = (const float*)d_in[0];
  const int*   mask   = (const int*)  d_in[1];
  const float* W_proj = (const float*)d_in[2];
  const float* b_proj = (const float*)d_in[3];
  const float* W_inv  = (const float*)d_in[4];
  const float* b_inv  = (const float*)d_in[5];
  const float* emb    = (const float*)d_in[6];

  const int N = in_sizes[1];          // 65536 tokens (32*2048)

  float* quant    = (float*)d_out;                    // [N][512]
  float* code_out = quant + (size_t)N * EMB;          // [N] as float
  float* loss_out = code_out + N;                     // [1]

  float* ws = (float*)d_ws;
  float* Ap = ws;                                     // [N][32] masked soft assign
  float* Cw = Ap + (size_t)N * MCODES;                // [32][512] = En @ W_inv
  float* G  = Cw + MCODES * EMB;                      // [32][32]  = 2*En
  float* qv = G + MCODES * VQ;                        // [32]      = ||En||^2

  prep_kernel<<<MCODES, 256, 0, stream>>>(emb, W_inv, Cw, G, qv, loss_out);
  proj_kernel<<<N / 32, 256, 0, stream>>>(h, mask, W_proj, b_proj, G, qv, Ap, code_out);
  inv_kernel<<<N / 64, 256, 0, stream>>>(Ap, Cw, b_inv, quant);
}

// Round 8
// 139.372 us; speedup vs baseline: 1.6176x; 1.6176x over previous
//
#include <hip/hip_runtime.h>
#include <math.h>

#define EMB 512
#define VQ 32
#define MCODES 32   // 2*LOG2
#define EPS 1e-8f

// ---------------------------------------------------------------------------
// prep: normalize codebook rows, G = 2*En, q = ||En||^2, C = En @ W_inv
// ---------------------------------------------------------------------------
__global__ __launch_bounds__(256)
void prep_kernel(const float* __restrict__ emb, const float* __restrict__ W_inv,
                 float* __restrict__ Cw, float* __restrict__ G, float* __restrict__ qv,
                 float* __restrict__ loss_out) {
  const int b = blockIdx.x;
  const int tid = threadIdx.x;
  __shared__ float En_s[VQ];
  float ss = 0.f;
#pragma unroll
  for (int d = 0; d < VQ; ++d) { float v = emb[b * VQ + d]; ss += v * v; }
  const float inv = 1.0f / (sqrtf(ss) + EPS);
  if (tid < VQ) En_s[tid] = emb[b * VQ + tid] * inv;
  __syncthreads();
  float a0 = 0.f, a1 = 0.f;
#pragma unroll 8
  for (int d = 0; d < VQ; ++d) {
    const float en = En_s[d];
    const float2 wv = ((const float2*)(W_inv + d * EMB))[tid];
    a0 += en * wv.x;
    a1 += en * wv.y;
  }
  ((float2*)(Cw + b * EMB))[tid] = make_float2(a0, a1);
  if (tid < VQ) G[b * VQ + tid] = 2.0f * En_s[tid];
  if (tid == 0) {
    float qq = 0.f;
#pragma unroll
    for (int d = 0; d < VQ; ++d) qq += En_s[d] * En_s[d];
    qv[b] = qq;
    if (b == 0) loss_out[0] = 0.0f;   // vq_loss
  }
}

// ---------------------------------------------------------------------------
// proj: R6 inner loop verbatim (4 tokens x 4 dims / thread, W amortized over
// 4 tokens), but 64-thread 1-wave blocks with 32 tokens -> 2048 blocks.
// R6 was grid-limited (512 blocks = 2/CU, Occ 19%, VALUBusy 16%); R7 showed
// 1-token/thread kills ILP (VALUBusy 10.6%). This keeps R6 ILP at 4x grid.
// ---------------------------------------------------------------------------
__global__ __launch_bounds__(64)
void proj_kernel(const float* __restrict__ h, const int* __restrict__ mask,
                 const float* __restrict__ W_proj, const float* __restrict__ b_proj,
                 const float* __restrict__ G, const float* __restrict__ qv,
                 float* __restrict__ Aout, float* __restrict__ code_out) {
  const int tid = threadIdx.x;
  const int slot = tid >> 3;   // 0..7 : token-slot within tile
  const int dg = tid & 7;      // 0..7 : dims 4*dg .. 4*dg+3
  const int tile = blockIdx.x * 32;
  __shared__ float hp_s[32][36];   // pitch 36 to break bank conflicts

  const float4* __restrict__ h4 = (const float4*)h;
  const float4* __restrict__ W4 = (const float4*)W_proj;   // [512][8] float4

  const float4* hr0 = h4 + (size_t)(tile + slot) * (EMB / 4);
  const float4* hr1 = hr0 + 8 * (EMB / 4);
  const float4* hr2 = hr1 + 8 * (EMB / 4);
  const float4* hr3 = hr2 + 8 * (EMB / 4);

  float4 a0 = make_float4(0.f, 0.f, 0.f, 0.f), a1 = a0, a2 = a0, a3 = a0;

  for (int e4 = 0; e4 < EMB / 4; ++e4) {
    const int eb = e4 << 2;
    const float4 w0 = W4[(eb + 0) * 8 + dg];
    const float4 w1 = W4[(eb + 1) * 8 + dg];
    const float4 w2 = W4[(eb + 2) * 8 + dg];
    const float4 w3 = W4[(eb + 3) * 8 + dg];
    const float4 v0 = hr0[e4];
    const float4 v1 = hr1[e4];
    const float4 v2 = hr2[e4];
    const float4 v3 = hr3[e4];
#define ACC4(A, V)                                                        \
    A.x += V.x * w0.x; A.x += V.y * w1.x; A.x += V.z * w2.x; A.x += V.w * w3.x; \
    A.y += V.x * w0.y; A.y += V.y * w1.y; A.y += V.z * w2.y; A.y += V.w * w3.y; \
    A.z += V.x * w0.z; A.z += V.y * w1.z; A.z += V.z * w2.z; A.z += V.w * w3.z; \
    A.w += V.x * w0.w; A.w += V.y * w1.w; A.w += V.z * w2.w; A.w += V.w * w3.w;
    ACC4(a0, v0) ACC4(a1, v1) ACC4(a2, v2) ACC4(a3, v3)
#undef ACC4
  }
  *(float4*)&hp_s[slot     ][dg * 4] = a0;
  *(float4*)&hp_s[slot +  8][dg * 4] = a1;
  *(float4*)&hp_s[slot + 16][dg * 4] = a2;
  *(float4*)&hp_s[slot + 24][dg * 4] = a3;
  __syncthreads();

  if (tid < 32) {
    const int t = tile + tid;
    const float4* bp4 = (const float4*)b_proj;
    float4 hp[8];
    float ssum = 0.f;
#pragma unroll
    for (int k = 0; k < 8; ++k) {
      float4 v = *(const float4*)&hp_s[tid][k * 4];
      const float4 b = bp4[k];
      v.x += b.x; v.y += b.y; v.z += b.z; v.w += b.w;
      hp[k] = v;
      ssum += v.x * v.x + v.y * v.y + v.z * v.z + v.w * v.w;
    }
    const float inv = 1.0f / (sqrtf(ssum) + EPS);
#pragma unroll
    for (int k = 0; k < 8; ++k) {
      hp[k].x *= inv; hp[k].y *= inv; hp[k].z *= inv; hp[k].w *= inv;
    }
    const float4* G4 = (const float4*)G;   // [32][8] float4, rows = 2*En_m
    float av[32];
    int code = 0;
#pragma unroll
    for (int g = 0; g < 16; ++g) {
      float d0 = 0.f, d1 = 0.f;
#pragma unroll
      for (int k = 0; k < 8; ++k) {
        const float4 g0 = G4[(2 * g) * 8 + k];
        const float4 g1 = G4[(2 * g + 1) * 8 + k];
        const float4 hv = hp[k];
        d0 += hv.x * g0.x + hv.y * g0.y + hv.z * g0.z + hv.w * g0.w;
        d1 += hv.x * g1.x + hv.y * g1.y + hv.z * g1.z + hv.w * g1.w;
      }
      // s_m = 2*hn.En_m - ||En_m||^2  (||hn||^2 cancels inside the pair softmax)
      const float s0 = d0 - qv[2 * g];
      const float s1 = d1 - qv[2 * g + 1];
      const float mx = fmaxf(s0, s1);
      const float e0 = expf(s0 - mx);
      const float e1 = expf(s1 - mx);
      const float rs = 1.0f / (e0 + e1);
      av[2 * g] = e0 * rs;
      av[2 * g + 1] = e1 * rs;
      code |= (e1 > e0) ? (1 << g) : 0;   // argmax, first index wins ties
    }
    const int mk = mask[t];
    const float msk = (mk == 1) ? 1.0f : 0.0f;
    float4* Ao = (float4*)(Aout + (size_t)t * MCODES);
#pragma unroll
    for (int k = 0; k < 8; ++k) {
      Ao[k] = make_float4(av[4 * k] * msk, av[4 * k + 1] * msk,
                          av[4 * k + 2] * msk, av[4 * k + 3] * msk);
    }
    code_out[t] = (mk == 1) ? (float)code : 0.0f;
  }
}

// ---------------------------------------------------------------------------
// inv: quantized = A' @ C + b_inv.  C columns (e-pair) resident in registers.
// ---------------------------------------------------------------------------
__global__ __launch_bounds__(256)
void inv_kernel(const float* __restrict__ Ap, const float* __restrict__ Cw,
                const float* __restrict__ b_inv, float* __restrict__ qout) {
  const int tid = threadIdx.x;
  const int w = tid >> 6;
  const int lane = tid & 63;
  const int ep = w * 64 + lane;      // e-pair index; e = 2*ep
  const int tile = blockIdx.x * 64;
  float2 c[32];
#pragma unroll
  for (int m = 0; m < 32; ++m) c[m] = ((const float2*)(Cw + m * EMB))[ep];
  const float2 bi = ((const float2*)b_inv)[ep];
  for (int tt = 0; tt < 64; ++tt) {
    const int t = tile + tt;
    const float4* a4 = (const float4*)(Ap + (size_t)t * 32);   // uniform address
    float accx = bi.x, accy = bi.y;
#pragma unroll
    for (int k = 0; k < 8; ++k) {
      const float4 a = a4[k];
      accx += a.x * c[4 * k].x + a.y * c[4 * k + 1].x + a.z * c[4 * k + 2].x + a.w * c[4 * k + 3].x;
      accy += a.x * c[4 * k].y + a.y * c[4 * k + 1].y + a.z * c[4 * k + 2].y + a.w * c[4 * k + 3].y;
    }
    ((float2*)(qout + (size_t)t * EMB))[ep] = make_float2(accx, accy);
  }
}

// ---------------------------------------------------------------------------
extern "C" void kernel_launch(void* const* d_in, const int* in_sizes, int n_in,
                              void* d_out, int out_size, void* d_ws, size_t ws_size,
                              hipStream_t stream) {
  (void)n_in; (void)out_size; (void)ws_size;
  const float* h      = (const float*)d_in[0];
  const int*   mask   = (const int*)  d_in[1];
  const float* W_proj = (const float*)d_in[2];
  const float* b_proj = (const float*)d_in[3];
  const float* W_inv  = (const float*)d_in[4];
  const float* b_inv  = (const float*)d_in[5];
  const float* emb    = (const float*)d_in[6];

  const int N = in_sizes[1];          // 65536 tokens (32*2048)

  float* quant    = (float*)d_out;                    // [N][512]
  float* code_out = quant + (size_t)N * EMB;          // [N] as float
  float* loss_out = code_out + N;                     // [1]

  float* ws = (float*)d_ws;
  float* Ap = ws;                                     // [N][32] masked soft assign
  float* Cw = Ap + (size_t)N * MCODES;                // [32][512] = En @ W_inv
  float* G  = Cw + MCODES * EMB;                      // [32][32]  = 2*En
  float* qv = G + MCODES * VQ;                        // [32]      = ||En||^2

  prep_kernel<<<MCODES, 256, 0, stream>>>(emb, W_inv, Cw, G, qv, loss_out);
  proj_kernel<<<N / 32, 64, 0, stream>>>(h, mask, W_proj, b_proj, G, qv, Ap, code_out);
  inv_kernel<<<N / 64, 256, 0, stream>>>(Ap, Cw, b_inv, quant);
}

// Round 9
// 130.583 us; speedup vs baseline: 1.7265x; 1.0673x over previous
//
#include <hip/hip_runtime.h>
#include <math.h>

#define EMB 512
#define VQ 32
#define MCODES 32   // 2*LOG2
#define EPS 1e-8f

// ---------------------------------------------------------------------------
// prep: normalize codebook rows, G = 2*En, q = ||En||^2, C = En @ W_inv
// ---------------------------------------------------------------------------
__global__ __launch_bounds__(256)
void prep_kernel(const float* __restrict__ emb, const float* __restrict__ W_inv,
                 float* __restrict__ Cw, float* __restrict__ G, float* __restrict__ qv,
                 float* __restrict__ loss_out) {
  const int b = blockIdx.x;
  const int tid = threadIdx.x;
  __shared__ float En_s[VQ];
  float ss = 0.f;
#pragma unroll
  for (int d = 0; d < VQ; ++d) { float v = emb[b * VQ + d]; ss += v * v; }
  const float inv = 1.0f / (sqrtf(ss) + EPS);
  if (tid < VQ) En_s[tid] = emb[b * VQ + tid] * inv;
  __syncthreads();
  float a0 = 0.f, a1 = 0.f;
#pragma unroll 8
  for (int d = 0; d < VQ; ++d) {
    const float en = En_s[d];
    const float2 wv = ((const float2*)(W_inv + d * EMB))[tid];
    a0 += en * wv.x;
    a1 += en * wv.y;
  }
  ((float2*)(Cw + b * EMB))[tid] = make_float2(a0, a1);
  if (tid < VQ) G[b * VQ + tid] = 2.0f * En_s[tid];
  if (tid == 0) {
    float qq = 0.f;
#pragma unroll
    for (int d = 0; d < VQ; ++d) qq += En_s[d] * En_s[d];
    qv[b] = qq;
    if (b == 0) loss_out[0] = 0.0f;   // vq_loss
  }
}

// ---------------------------------------------------------------------------
// proj, split-K: 256 threads = 4 waves; wave wv handles e-dims [128wv,128wv+128)
// for the block's 32 tokens (4 tokens x 4 dims per thread — R6's proven ILP).
// 2048 blocks x 4 waves = 8192 waves = 32 waves/CU (R6/R8 shipped only 2048
// waves total = 25% occupancy cap — the measured latency bottleneck).
// Partials combined in LDS; epilogue (norm/softmax/code) unchanged.
// ---------------------------------------------------------------------------
__global__ __launch_bounds__(256)
void proj_kernel(const float* __restrict__ h, const int* __restrict__ mask,
                 const float* __restrict__ W_proj, const float* __restrict__ b_proj,
                 const float* __restrict__ G, const float* __restrict__ qv,
                 float* __restrict__ Aout, float* __restrict__ code_out) {
  const int tid = threadIdx.x;
  const int wv = tid >> 6;     // 0..3 : K-slice
  const int lane = tid & 63;
  const int slot = lane >> 3;  // 0..7 : token-slot
  const int dg = lane & 7;     // 0..7 : out-dims 4*dg .. 4*dg+3
  const int tile = blockIdx.x * 32;
  __shared__ float hp_s[4][32][36];   // [kslice][token][dim], pitch 36

  const float4* __restrict__ h4 = (const float4*)h;
  const float4* __restrict__ W4 = (const float4*)W_proj;   // [512][8] float4

  const int e4base = wv * 32;          // float4 units; e-base = 128*wv
  const float4* hr0 = h4 + (size_t)(tile + slot) * (EMB / 4) + e4base;
  const float4* hr1 = hr0 + 8 * (EMB / 4);
  const float4* hr2 = hr1 + 8 * (EMB / 4);
  const float4* hr3 = hr2 + 8 * (EMB / 4);

  float4 a0 = make_float4(0.f, 0.f, 0.f, 0.f), a1 = a0, a2 = a0, a3 = a0;

  for (int e4 = 0; e4 < 32; ++e4) {
    const int eb = (e4base + e4) << 2;
    const float4 w0 = W4[(eb + 0) * 8 + dg];
    const float4 w1 = W4[(eb + 1) * 8 + dg];
    const float4 w2 = W4[(eb + 2) * 8 + dg];
    const float4 w3 = W4[(eb + 3) * 8 + dg];
    const float4 v0 = hr0[e4];
    const float4 v1 = hr1[e4];
    const float4 v2 = hr2[e4];
    const float4 v3 = hr3[e4];
#define ACC4(A, V)                                                        \
    A.x += V.x * w0.x; A.x += V.y * w1.x; A.x += V.z * w2.x; A.x += V.w * w3.x; \
    A.y += V.x * w0.y; A.y += V.y * w1.y; A.y += V.z * w2.y; A.y += V.w * w3.y; \
    A.z += V.x * w0.z; A.z += V.y * w1.z; A.z += V.z * w2.z; A.z += V.w * w3.z; \
    A.w += V.x * w0.w; A.w += V.y * w1.w; A.w += V.z * w2.w; A.w += V.w * w3.w;
    ACC4(a0, v0) ACC4(a1, v1) ACC4(a2, v2) ACC4(a3, v3)
#undef ACC4
  }
  *(float4*)&hp_s[wv][slot     ][dg * 4] = a0;
  *(float4*)&hp_s[wv][slot +  8][dg * 4] = a1;
  *(float4*)&hp_s[wv][slot + 16][dg * 4] = a2;
  *(float4*)&hp_s[wv][slot + 24][dg * 4] = a3;
  __syncthreads();

  if (tid < 32) {
    const int t = tile + tid;
    const float4* bp4 = (const float4*)b_proj;
    float4 hp[8];
    float ssum = 0.f;
#pragma unroll
    for (int k = 0; k < 8; ++k) {
      float4 p0 = *(const float4*)&hp_s[0][tid][k * 4];
      const float4 p1 = *(const float4*)&hp_s[1][tid][k * 4];
      const float4 p2 = *(const float4*)&hp_s[2][tid][k * 4];
      const float4 p3 = *(const float4*)&hp_s[3][tid][k * 4];
      const float4 b = bp4[k];
      float4 v;
      v.x = ((p0.x + p1.x) + p2.x) + p3.x + b.x;
      v.y = ((p0.y + p1.y) + p2.y) + p3.y + b.y;
      v.z = ((p0.z + p1.z) + p2.z) + p3.z + b.z;
      v.w = ((p0.w + p1.w) + p2.w) + p3.w + b.w;
      hp[k] = v;
      ssum += v.x * v.x + v.y * v.y + v.z * v.z + v.w * v.w;
    }
    const float inv = 1.0f / (sqrtf(ssum) + EPS);
#pragma unroll
    for (int k = 0; k < 8; ++k) {
      hp[k].x *= inv; hp[k].y *= inv; hp[k].z *= inv; hp[k].w *= inv;
    }
    const float4* G4 = (const float4*)G;   // [32][8] float4, rows = 2*En_m
    float av[32];
    int code = 0;
#pragma unroll
    for (int g = 0; g < 16; ++g) {
      float d0 = 0.f, d1 = 0.f;
#pragma unroll
      for (int k = 0; k < 8; ++k) {
        const float4 g0 = G4[(2 * g) * 8 + k];
        const float4 g1 = G4[(2 * g + 1) * 8 + k];
        const float4 hv = hp[k];
        d0 += hv.x * g0.x + hv.y * g0.y + hv.z * g0.z + hv.w * g0.w;
        d1 += hv.x * g1.x + hv.y * g1.y + hv.z * g1.z + hv.w * g1.w;
      }
      // s_m = 2*hn.En_m - ||En_m||^2  (||hn||^2 cancels inside the pair softmax)
      const float s0 = d0 - qv[2 * g];
      const float s1 = d1 - qv[2 * g + 1];
      const float mx = fmaxf(s0, s1);
      const float e0 = expf(s0 - mx);
      const float e1 = expf(s1 - mx);
      const float rs = 1.0f / (e0 + e1);
      av[2 * g] = e0 * rs;
      av[2 * g + 1] = e1 * rs;
      code |= (e1 > e0) ? (1 << g) : 0;   // argmax, first index wins ties
    }
    const int mk = mask[t];
    const float msk = (mk == 1) ? 1.0f : 0.0f;
    float4* Ao = (float4*)(Aout + (size_t)t * MCODES);
#pragma unroll
    for (int k = 0; k < 8; ++k) {
      Ao[k] = make_float4(av[4 * k] * msk, av[4 * k + 1] * msk,
                          av[4 * k + 2] * msk, av[4 * k + 3] * msk);
    }
    code_out[t] = (mk == 1) ? (float)code : 0.0f;
  }
}

// ---------------------------------------------------------------------------
// inv: quantized = A' @ C + b_inv.  C columns (e-pair) resident in registers.
// ---------------------------------------------------------------------------
__global__ __launch_bounds__(256)
void inv_kernel(const float* __restrict__ Ap, const float* __restrict__ Cw,
                const float* __restrict__ b_inv, float* __restrict__ qout) {
  const int tid = threadIdx.x;
  const int w = tid >> 6;
  const int lane = tid & 63;
  const int ep = w * 64 + lane;      // e-pair index; e = 2*ep
  const int tile = blockIdx.x * 64;
  float2 c[32];
#pragma unroll
  for (int m = 0; m < 32; ++m) c[m] = ((const float2*)(Cw + m * EMB))[ep];
  const float2 bi = ((const float2*)b_inv)[ep];
  for (int tt = 0; tt < 64; ++tt) {
    const int t = tile + tt;
    const float4* a4 = (const float4*)(Ap + (size_t)t * 32);   // uniform address
    float accx = bi.x, accy = bi.y;
#pragma unroll
    for (int k = 0; k < 8; ++k) {
      const float4 a = a4[k];
      accx += a.x * c[4 * k].x + a.y * c[4 * k + 1].x + a.z * c[4 * k + 2].x + a.w * c[4 * k + 3].x;
      accy += a.x * c[4 * k].y + a.y * c[4 * k + 1].y + a.z * c[4 * k + 2].y + a.w * c[4 * k + 3].y;
    }
    ((float2*)(qout + (size_t)t * EMB))[ep] = make_float2(accx, accy);
  }
}

// ---------------------------------------------------------------------------
extern "C" void kernel_launch(void* const* d_in, const int* in_sizes, int n_in,
                              void* d_out, int out_size, void* d_ws, size_t ws_size,
                              hipStream_t stream) {
  (void)n_in; (void)out_size; (void)ws_size;
  const float* h      = (const float*)d_in[0];
  const int*   mask   = (const int*)  d_in[1];
  const float* W_proj = (const float*)d_in[2];
  const float* b_proj = (const float*)d_in[3];
  const float* W_inv  = (const float*)d_in[4];
  const float* b_inv  = (const float*)d_in[5];
  const float* emb    = (const float*)d_in[6];

  const int N = in_sizes[1];          // 65536 tokens (32*2048)

  float* quant    = (float*)d_out;                    // [N][512]
  float* code_out = quant + (size_t)N * EMB;          // [N] as float
  float* loss_out = code_out + N;                     // [1]

  float* ws = (float*)d_ws;
  float* Ap = ws;                                     // [N][32] masked soft assign
  float* Cw = Ap + (size_t)N * MCODES;                // [32][512] = En @ W_inv
  float* G  = Cw + MCODES * EMB;                      // [32][32]  = 2*En
  float* qv = G + MCODES * VQ;                        // [32]      = ||En||^2

  prep_kernel<<<MCODES, 256, 0, stream>>>(emb, W_inv, Cw, G, qv, loss_out);
  proj_kernel<<<N / 32, 256, 0, stream>>>(h, mask, W_proj, b_proj, G, qv, Ap, code_out);
  inv_kernel<<<N / 64, 256, 0, stream>>>(Ap, Cw, b_inv, quant);
}